// Round 9
// baseline (209.977 us; speedup 1.0000x reference)
//
#include <hip/hip_runtime.h>

#define LENF 15
#define NZ   1e-5f

typedef float f32x2 __attribute__((ext_vector_type(2)));
typedef float f32x4 __attribute__((ext_vector_type(4)));

struct R3 { float p, t, e; };   // 12B record -> global_load_dwordx3

__device__ __forceinline__ void uh_weights(float a, float b, float* w) {
  // gamma UH; lgamma/theta terms cancel under normalization
  float lw[LENF], m = -1e30f;
  const float ib = 1.f / b;
#pragma unroll
  for (int l = 0; l < LENF; ++l) {
    float tt = l + 0.5f;
    lw[l] = (a - 1.f) * __logf(tt) - tt * ib;
    m = fmaxf(m, lw[l]);
  }
  float s = 0.f;
#pragma unroll
  for (int l = 0; l < LENF; ++l) { w[l] = __expf(lw[l] - m); s += w[l]; }
  const float r = 1.f / s;
#pragma unroll
  for (int l = 0; l < LENF; ++l) w[l] *= r;
}

// 2-wave producer/consumer pipeline per block (64 cells/block):
//   wave1 (producer): x loads, PREP (all transcendentals), FIR2(w2,qd), store
//   wave0 (consumer): serial recurrence + FIR1(w1,qx)
// LDS ping-pong, one __syncthreads per 15-step chunk (uniform site).
__global__ __launch_bounds__(128, 1) void exphydro_pipe(
    const float* __restrict__ x,      // (T, G, 3)
    const float* __restrict__ params, // (G, 16)
    float* __restrict__ out,          // (T, G)
    int G, int T)
{
  __shared__ f32x4 sPrep[2][LENF][64];   // {pf, snow, mp, rain}
  __shared__ float sRp[2][LENF][64];     // ET_eff * pet
  __shared__ f32x2 sOQ[2][LENF][64];     // {o1 = FIR1 out, qd}

  const int lane = threadIdx.x & 63;
  const int wid  = threadIdx.x >> 6;
  const int g    = blockIdx.x * 64 + lane;
  const bool valid = (g < G);
  const int gs   = valid ? g : (G - 1);

  const float* pp = params + (size_t)gs * 16;
  const int nb = (T + LENF - 1) / LENF;   // chunks; only last may be partial
  const unsigned Gu = (unsigned)G;
  const R3* xg = (const R3*)x + gs;       // record idx = t*G + gs (<2^31 B)

  // producer state (wave1)
  R3 XA[LENF], XB[LENF];
  float w2[LENF], D2[LENF - 1];
  float Kf = 0, exp_fe = 0, Tbf = 0, ddf = 0, mpb = 0, ET_eff = 0;
  // consumer state (wave0)
  float w1[LENF], D1[LENF - 1];
  float wrf = 0, c_vad = 0, c_phr = 0, vml = 0, crp = 0, cvp = 0;
  float sog = NZ, wis = NZ, vad = NZ, phr = NZ;

  if (wid == 1) {
    ddf    = pp[0] * 40.f;
    mpb    = ddf * (pp[1] * 5.f - 2.f);   // melt bias = ddf*Tbm
    Tbf    = pp[3] * 7.f - 5.f;
    Kf     = pp[4] * 5.f;
    exp_fe = pp[5];
    ET_eff = pp[6];
    uh_weights(pp[14] * (13.f - 0.5f) + 0.5f,
               pp[15] * (1.5f - 0.15f) + 0.15f, w2);
#pragma unroll
    for (int l = 0; l < LENF - 1; ++l) D2[l] = 0.f;
  } else {
    wrf   = pp[2] * 0.5f;
    c_vad = pp[9] * 0.1f;
    c_phr = pp[10] * (0.01f - 1e-5f) + 1e-5f;
    vml   = pp[11] * (500.f - 0.001f) + 0.001f;
    const float inv_vml = 1.f / vml;
    crp = pp[7] * inv_vml;                              // c_run/vml
    cvp = (pp[8] * (0.02f - 1e-5f) + 1e-5f) * inv_vml;  // c_v2p/vml
    uh_weights(pp[12] * (20.f - 0.3f) + 0.3f,
               pp[13] * (5.f - 0.01f) + 0.01f, w1);
#pragma unroll
    for (int l = 0; l < LENF - 1; ++l) D1[l] = 0.f;
  }

#define LOADC(BUF, c)                                                  \
  {                                                                    \
    unsigned tb_ = (unsigned)(c) * LENF;                               \
    _Pragma("unroll")                                                  \
    for (int j = 0; j < LENF; ++j) {                                   \
      unsigned t_ = tb_ + (unsigned)j;                                 \
      if (t_ > (unsigned)(T - 1)) t_ = (unsigned)(T - 1);              \
      BUF[j] = xg[t_ * Gu];                                            \
    }                                                                  \
  }

#define PREPC(BUF, c)                                                  \
  {                                                                    \
    const int pb_ = (c) & 1;                                           \
    _Pragma("unroll")                                                  \
    for (int j = 0; j < LENF; ++j) {                                   \
      float p_ = BUF[j].p, tm_ = BUF[j].t;                             \
      float rain_ = (tm_ >= 0.f) ? p_ : 0.f;                           \
      f32x4 pr_;                                                       \
      pr_.x = Kf * __builtin_amdgcn_exp2f(                             \
          exp_fe * __builtin_amdgcn_logf(fmaxf(Tbf - tm_, NZ)));       \
      pr_.y = p_ - rain_;                                              \
      pr_.z = fmaxf(ddf * tm_ - mpb, 0.f);                             \
      pr_.w = rain_;                                                   \
      sPrep[pb_][j][lane] = pr_;                                       \
      sRp[pb_][j][lane] = ET_eff * BUF[j].e;                           \
    }                                                                  \
  }

#define CONVC(c, cnt)                                                  \
  {                                                                    \
    const int pb_ = (c) & 1;                                           \
    const unsigned t0_ = (unsigned)(c) * LENF;                         \
    _Pragma("unroll")                                                  \
    for (int i = 0; i < LENF; ++i) {                                   \
      if (i < (cnt)) {                                                 \
        f32x2 q_ = sOQ[pb_][i][lane];                                  \
        float o2_ = D2[0] + w2[0] * q_.y;                              \
        _Pragma("unroll")                                              \
        for (int l = 0; l < LENF - 2; ++l)                             \
          D2[l] = D2[l + 1] + w2[l + 1] * q_.y;                        \
        D2[LENF - 2] = w2[LENF - 1] * q_.y;                            \
        if (valid)                                                     \
          out[(size_t)((t0_ + (unsigned)i) * Gu + (unsigned)g)] =      \
              q_.x + o2_;                                              \
      }                                                                \
    }                                                                  \
  }

#define STEPSC(k, cnt)                                                 \
  {                                                                    \
    const int pb_ = (k) & 1;                                           \
    _Pragma("unroll")                                                  \
    for (int i = 0; i < LENF; ++i) {                                   \
      if (i < (cnt)) {                                                 \
        f32x4 pr_ = sPrep[pb_][i][lane];                               \
        float rp_ = sRp[pb_][i][lane];                                 \
        float freeze = fminf(pr_.x, wis);                              \
        wis -= freeze;                                                 \
        float sos = sog + freeze + pr_.y;                              \
        float melt = fminf(pr_.z, sos);                                \
        sog = sos - melt;                                              \
        float ret = wrf * sog;                                         \
        float wtmp = wis + melt + pr_.w;                               \
        float avail = fmaxf(wtmp - ret, 0.f);                          \
        wis = fminf(wtmp, ret);      /* == avail>0 ? ret : wtmp */     \
        float t1_ = crp * vad;                                         \
        float ht0 = t1_ * avail;                                       \
        float t2_ = cvp * vad;                                         \
        float ht1 = t2_ * vad;                                         \
        float ht2 = c_vad * vad;                                       \
        float ht3 = c_phr * phr;                                       \
        float infil = avail - ht0;                                     \
        float aet = fminf(rp_, vad);                                   \
        float v2_ = vad + infil - aet - ht1 - ht2;                     \
        float overflow = fmaxf(v2_ - vml, 0.f);                        \
        vad = fminf(fmaxf(v2_, NZ), vml);     /* v_med3_f32 */         \
        float qx = ht0 + overflow;                                     \
        phr = fmaxf(phr + ht1 - ht3, NZ);                              \
        float qd = ht2 + ht3;                                          \
        float o1 = D1[0] + w1[0] * qx;                                 \
        _Pragma("unroll")                                              \
        for (int l = 0; l < LENF - 2; ++l)                             \
          D1[l] = D1[l + 1] + w1[l + 1] * qx;                          \
        D1[LENF - 2] = w1[LENF - 1] * qx;                              \
        sOQ[pb_][i][lane] = (f32x2){o1, qd};                           \
      }                                                                \
    }                                                                  \
  }

  // Pipeline: iter k => wave1 {load chunk k+2, conv chunk k-1, prep chunk k+1}
  //                     wave0 {recurrence chunk k}
  // k = -1 is the prologue (load chunk 0/1, prep chunk 0). Barrier is at a
  // single uniform site per iteration.
  for (int k = -1; k < nb; ++k) {
    if (wid == 1) {
      if (k < 0) {
        LOADC(XA, 0);
        if (nb > 1) LOADC(XB, 1);
        PREPC(XA, 0);
      } else {
        const int c2 = k + 2;
        if (c2 < nb) {
          if (c2 & 1) { LOADC(XB, c2); } else { LOADC(XA, c2); }
        }
        if (k > 0) { CONVC(k - 1, LENF); }   // chunks 0..nb-2 are full
        const int c1 = k + 1;
        if (c1 < nb) {
          if (c1 & 1) { PREPC(XB, c1); } else { PREPC(XA, c1); }
        }
      }
    } else {
      if (k >= 0) {
        int cnt = T - k * LENF; if (cnt > LENF) cnt = LENF;
        STEPSC(k, cnt);
      }
    }
    __syncthreads();
  }
  if (wid == 1) {                       // drain: conv of the last chunk
    int cl = T - (nb - 1) * LENF;
    CONVC(nb - 1, cl);
  }

#undef LOADC
#undef PREPC
#undef CONVC
#undef STEPSC
}

extern "C" void kernel_launch(void* const* d_in, const int* in_sizes, int n_in,
                              void* d_out, int out_size, void* d_ws, size_t ws_size,
                              hipStream_t stream) {
  const float* x      = (const float*)d_in[0];
  const float* params = (const float*)d_in[1];
  float* out          = (float*)d_out;

  int G = in_sizes[1] / 16;               // 15000
  int T = in_sizes[0] / (G * 3);          // 1095

  int block = 128;                        // 2 waves: producer + consumer
  int grid  = (G + 63) / 64;              // 64 cells per block
  exphydro_pipe<<<grid, block, 0, stream>>>(x, params, out, G, T);
}

// Round 10
// 193.726 us; speedup vs baseline: 1.0839x; 1.0839x over previous
//
#include <hip/hip_runtime.h>

#define LENF 15
#define BLK  5
#define NZ   1e-5f

typedef float f32x2 __attribute__((ext_vector_type(2)));

struct R3 { float p, t, e; };   // 12B record -> global_load_dwordx3

__global__ __launch_bounds__(64, 1) void exphydro_kernel(
    const float* __restrict__ x,      // (T, G, 3): prcp, tmean, pet
    const float* __restrict__ params, // (G, 16)
    float* __restrict__ out,          // (T, G)
    int G, int T)
{
  int g = blockIdx.x * 64 + threadIdx.x;
  if (g >= G) return;

  // ---- params (+ pre-combined constants) ----
  const float* pp = params + (size_t)g * 16;
  float P0[16];
#pragma unroll
  for (int i = 0; i < 16; ++i) P0[i] = pp[i];

  const float ddf    = P0[0]  * 40.f;
  const float Tbm    = P0[1]  * 5.f  - 2.f;
  const float wrf    = P0[2]  * 0.5f;
  const float Tbf    = P0[3]  * 7.f  - 5.f;
  const float Kf     = P0[4]  * 5.f;
  const float exp_fe = P0[5];
  const float ET_eff = P0[6];
  const float c_vad  = P0[9]  * 0.1f;
  const float c_phr  = P0[10] * (0.01f - 1e-5f) + 1e-5f;
  const float vml    = P0[11] * (500.f - 0.001f) + 0.001f;
  const float inv_vml = 1.f / vml;
  const float crp    = P0[7] * inv_vml;                             // c_run/vml
  const float cvp    = (P0[8] * (0.02f - 1e-5f) + 1e-5f) * inv_vml; // c_v2p/vml
  const float mpb    = ddf * Tbm;                                   // melt bias
  const float a1     = P0[12] * (20.f - 0.3f)  + 0.3f;
  const float b1     = P0[13] * (5.f  - 0.01f) + 0.01f;
  const float a2     = P0[14] * (13.f - 0.5f)  + 0.5f;
  const float b2     = P0[15] * (1.5f - 0.15f) + 0.15f;

  // ---- gamma UH weights (lgamma/theta terms cancel under normalization) ----
  f32x2 wv[LENF];
  {
    float lw1[LENF], lw2[LENF];
    float m1 = -1e30f, m2 = -1e30f;
    const float ib1 = 1.f / b1, ib2 = 1.f / b2;
#pragma unroll
    for (int l = 0; l < LENF; ++l) {
      float tt = l + 0.5f;
      float lt = __logf(tt);
      lw1[l] = (a1 - 1.f) * lt - tt * ib1;
      lw2[l] = (a2 - 1.f) * lt - tt * ib2;
      m1 = fmaxf(m1, lw1[l]);
      m2 = fmaxf(m2, lw2[l]);
    }
    float s1 = 0.f, s2 = 0.f;
    float t1[LENF], t2[LENF];
#pragma unroll
    for (int l = 0; l < LENF; ++l) {
      t1[l] = __expf(lw1[l] - m1); s1 += t1[l];
      t2[l] = __expf(lw2[l] - m2); s2 += t2[l];
    }
    const float r1 = 1.f / s1, r2 = 1.f / s2;
#pragma unroll
    for (int l = 0; l < LENF; ++l) { wv[l].x = t1[l] * r1; wv[l].y = t2[l] * r2; }
  }

  // ---- state ----
  float sog = NZ, wis = NZ;            // P1 state (one chunk AHEAD)
  float vad = NZ, phr = NZ;            // P2 state
  f32x2 D[LENF - 1];                   // transposed-FIR delay line (P2)
#pragma unroll
  for (int l = 0; l < LENF - 1; ++l) D[l] = (f32x2){0.f, 0.f};

  const unsigned Gu = (unsigned)G;
  const R3* xg = (const R3*)x + g;     // record idx = t*G + g (<2^31 bytes)
  unsigned oof = (unsigned)g;          // running output index (P2 order)
  const unsigned tmax = (unsigned)(T - 1);

  R3 XA[BLK], XB[BLK];                 // input staging, ping-pong
  float pf[BLK], mp[BLK];              // PREP (trans off both chains)
  float avail[BLK], rp[BLK];           // P1 -> P2 hand-off (read-before-write)

  const int nc = (T + BLK - 1) / BLK;  // 219 for T=1095

#define LOADC(BUF, c)                                                 \
  {                                                                   \
    unsigned tb_ = (unsigned)(c) * (unsigned)BLK;                     \
    _Pragma("unroll")                                                 \
    for (int j = 0; j < BLK; ++j) {                                   \
      unsigned t_ = tb_ + (unsigned)j;                                \
      if (t_ > tmax) t_ = tmax;                                       \
      BUF[j] = xg[t_ * Gu];                                           \
    }                                                                 \
  }

  // transcendentals: pure input functions, issued before both chains
#define PREPC(BUF, cnt)                                               \
  {                                                                   \
    _Pragma("unroll")                                                 \
    for (int j = 0; j < BLK; ++j) {                                   \
      if (j < (cnt)) {                                                \
        float tm_ = BUF[j].t;                                         \
        pf[j] = Kf * __builtin_amdgcn_exp2f(                          \
            exp_fe * __builtin_amdgcn_logf(fmaxf(Tbf - tm_, NZ)));    \
        mp[j] = fmaxf(ddf * tm_ - mpb, 0.f);                          \
      }                                                               \
    }                                                                 \
  }

  // P1 (snow/ice chain): consumes pf/mp + raw input, produces avail/rp
#define P1STEP(BUF, J_)                                               \
  {                                                                   \
    float p_ = BUF[J_].p, tm_ = BUF[J_].t;                            \
    float rain = (tm_ >= 0.f) ? p_ : 0.f;                             \
    float snow = p_ - rain;                                           \
    float freeze = fminf(pf[J_], wis);                                \
    wis -= freeze;                                                    \
    float sos = sog + freeze + snow;                                  \
    float melt = fminf(mp[J_], sos);                                  \
    sog = sos - melt;                                                 \
    float ret = wrf * sog;                                            \
    float wtmp = wis + melt + rain;                                   \
    avail[J_] = fmaxf(wtmp - ret, 0.f);                               \
    wis = fminf(wtmp, ret);       /* == avail>0 ? ret : wtmp */       \
    rp[J_] = ET_eff * BUF[J_].e;                                      \
  }

  // P2 (soil chain + FIR + store): consumes avail/rp of the PREVIOUS chunk
#define P2STEP(J_)                                                    \
  {                                                                   \
    float av_ = avail[J_], rp_ = rp[J_];                              \
    float t1_ = crp * vad;                                            \
    float ht0 = t1_ * av_;                                            \
    float t2_ = cvp * vad;                                            \
    float ht1 = t2_ * vad;                                            \
    float ht2 = c_vad * vad;                                          \
    float ht3 = c_phr * phr;                                          \
    float infil = av_ - ht0;                                          \
    float aet = fminf(rp_, vad);                                      \
    float v2_ = vad + infil - aet - ht1 - ht2;                        \
    float overflow = fmaxf(v2_ - vml, 0.f);                           \
    vad = fminf(fmaxf(v2_, NZ), vml);        /* v_med3_f32 */         \
    float qx = ht0 + overflow;                                        \
    phr = fmaxf(phr + ht1 - ht3, NZ);                                 \
    f32x2 q_; q_.x = qx; q_.y = ht2 + ht3;                            \
    f32x2 o_ = D[0] + wv[0] * q_;                                     \
    _Pragma("unroll")                                                 \
    for (int l = 0; l < LENF - 2; ++l)                                \
      D[l] = D[l + 1] + wv[l + 1] * q_;        /* v_pk_fma_f32 */     \
    D[LENF - 2] = wv[LENF - 1] * q_;                                  \
    out[oof] = o_.x + o_.y;                                           \
    oof += Gu;                                                        \
  }

  // P2(chunk k-1, step j) BEFORE P1(chunk k, step j): read-before-write on
  // avail[j]/rp[j]. Two independent chains -> instruction-level overlap.
#define CHUNK(BUF, p1cnt, p2cnt)                                      \
  {                                                                   \
    PREPC(BUF, p1cnt);                                                \
    _Pragma("unroll")                                                 \
    for (int j = 0; j < BLK; ++j) {                                   \
      if (j < (p2cnt)) P2STEP(j);                                     \
      if (j < (p1cnt)) P1STEP(BUF, j);                                \
    }                                                                 \
  }

  // ---- prologue: chunk 0 is P1-only ----
  if (nc > 0) LOADC(XA, 0);
  if (nc > 1) LOADC(XB, 1);
  {
    int c0 = (T < BLK) ? T : BLK;
    PREPC(XA, c0);
#pragma unroll
    for (int j = 0; j < BLK; ++j) if (j < c0) P1STEP(XA, j);
  }

  int k = 1;
  // ---- full-pair region: chunks k and k+1 both full ----
  while ((k + 2) * BLK <= T) {
    LOADC(XA, k + 1);                 // chunk k+1 (prefetch into dead XA)
    CHUNK(XB, BLK, BLK);              // P1 chunk k, P2 chunk k-1
    if (k + 2 < nc) LOADC(XB, k + 2);
    CHUNK(XA, BLK, BLK);              // P1 chunk k+1, P2 chunk k
    k += 2;
  }
  // ---- generic tail chunks (0..2 iterations) ----
  while (k < nc) {
    if (k + 1 < nc) {
      if ((k + 1) & 1) { LOADC(XB, k + 1); } else { LOADC(XA, k + 1); }
    }
    int p1c = T - k * BLK; if (p1c > BLK) p1c = BLK;
    if (k & 1) { CHUNK(XB, p1c, BLK); } else { CHUNK(XA, p1c, BLK); }
    ++k;
  }
  // ---- epilogue: P2 for the last chunk ----
  {
    int p2c = T - (nc - 1) * BLK;
#pragma unroll
    for (int j = 0; j < BLK; ++j) if (j < p2c) P2STEP(j);
  }

#undef LOADC
#undef PREPC
#undef P1STEP
#undef P2STEP
#undef CHUNK
}

extern "C" void kernel_launch(void* const* d_in, const int* in_sizes, int n_in,
                              void* d_out, int out_size, void* d_ws, size_t ws_size,
                              hipStream_t stream) {
  const float* x      = (const float*)d_in[0];
  const float* params = (const float*)d_in[1];
  float* out          = (float*)d_out;

  int G = in_sizes[1] / 16;               // 15000
  int T = in_sizes[0] / (G * 3);          // 1095

  int block = 64;                         // 1 wave/block -> 235 waves on 235 CUs
  int grid  = (G + block - 1) / block;
  exphydro_kernel<<<grid, block, 0, stream>>>(x, params, out, G, T);
}